// Round 1
// baseline (400.497 us; speedup 1.0000x reference)
//
#include <hip/hip_runtime.h>

#define SEQ  2048
#define RDIM 384
#define CDIM 64

// XOR-swizzled transposed LDS layout: element (k, row) of a [64 k][128 row] tile.
// 8-float groups stay contiguous (b128-friendly); group index XORed with k>>2 so
// GEMM A-reads (rows 8rt..8rt+7, fixed k) are broadcast/conflict-free while the
// LN staging writes (fixed row, k = 4*c4+i varying per lane) are only 4-way.
#define XOFF(k,row) (((k)<<7) + (((((row)>>3) ^ (((k)>>2)&15)))<<3) + ((row)&7))

__device__ __forceinline__ float sigmoidf_(float z) { return 1.0f / (1.0f + __expf(-z)); }

// ---------------- Phase 1: LN + q_avg partials + k/v projection ----------------
__global__ __launch_bounds__(256) void k_phase1(
    const float* __restrict__ x, const float* __restrict__ lnw, const float* __restrict__ lnb,
    const float* __restrict__ Wk, const float* __restrict__ Wv,
    float* __restrict__ qpart, float* __restrict__ kv)
{
    __shared__ float wkv[64 * 16];   // col j<8 : Wk[:,j] ; col j>=8 : Wv[:,j-8]
    const int t = threadIdx.x;
    if (t < 64) {
        #pragma unroll
        for (int j = 0; j < 8; j++) wkv[t * 16 + j]     = Wk[t * 8 + j];
        #pragma unroll
        for (int j = 0; j < 8; j++) wkv[t * 16 + 8 + j] = Wv[t * 8 + j];
    }
    const int rtile  = blockIdx.x % 24;
    const int schunk = blockIdx.x / 24;
    const int rloc = t >> 4;     // 0..15 : row within tile (16-lane groups share a row)
    const int c4   = t & 15;     // 0..15 : float4 column within the row
    const int r = rtile * 16 + rloc;
    const float4 lw = *(const float4*)(lnw + (c4 << 2));
    const float4 lb = *(const float4*)(lnb + (c4 << 2));
    __syncthreads();

    float qs0 = 0.f, qs1 = 0.f, qs2 = 0.f, qs3 = 0.f;
    for (int sl = 0; sl < 64; sl++) {
        const int s = schunk * 64 + sl;
        const float4 xv = *(const float4*)(x + ((size_t)s * RDIM + r) * CDIM + (c4 << 2));
        float sum = xv.x + xv.y + xv.z + xv.w;
        float sq  = xv.x * xv.x + xv.y * xv.y + xv.z * xv.z + xv.w * xv.w;
        #pragma unroll
        for (int m = 1; m < 16; m <<= 1) {
            sum += __shfl_xor(sum, m, 16);
            sq  += __shfl_xor(sq,  m, 16);
        }
        const float mu   = sum * (1.0f / 64.0f);
        const float rstd = rsqrtf(sq * (1.0f / 64.0f) - mu * mu + 1e-5f);
        const float xn0 = (xv.x - mu) * rstd * lw.x + lb.x;
        const float xn1 = (xv.y - mu) * rstd * lw.y + lb.y;
        const float xn2 = (xv.z - mu) * rstd * lw.z + lb.z;
        const float xn3 = (xv.w - mu) * rstd * lw.w + lb.w;
        qs0 += xn0; qs1 += xn1; qs2 += xn2; qs3 += xn3;

        // lane j = c4 computes (k|v)[j] = sum_i xn[i] * wkv[i][j] via shfl broadcast
        float o = 0.f;
        #pragma unroll
        for (int ii = 0; ii < 16; ii++) {
            const float b0 = __shfl(xn0, ii, 16);
            const float b1 = __shfl(xn1, ii, 16);
            const float b2 = __shfl(xn2, ii, 16);
            const float b3 = __shfl(xn3, ii, 16);
            o += b0 * wkv[(ii * 4 + 0) * 16 + c4] + b1 * wkv[(ii * 4 + 1) * 16 + c4]
               + b2 * wkv[(ii * 4 + 2) * 16 + c4] + b3 * wkv[(ii * 4 + 3) * 16 + c4];
        }
        kv[((size_t)r * SEQ + s) * 16 + c4] = o;
    }
    float4 q4; q4.x = qs0; q4.y = qs1; q4.z = qs2; q4.w = qs3;
    *(float4*)(qpart + ((size_t)schunk * RDIM + r) * CDIM + (c4 << 2)) = q4;
}

// ---------------- Reduce q_avg partials (deterministic) ----------------
__global__ __launch_bounds__(256) void k_reduce(
    const float* __restrict__ qpart, float* __restrict__ qavg)
{
    const int g = blockIdx.x * 256 + threadIdx.x;   // 0..24575
    float s = 0.f;
    #pragma unroll
    for (int ch = 0; ch < 32; ch++) s += qpart[(size_t)ch * (RDIM * CDIM) + g];
    qavg[g] = s;   // still the SUM over s; scale applied in phase 2
}

// ---------------- Phase 2: q, logits, softmax, o ----------------
__global__ __launch_bounds__(256) void k_phase2(
    const float* __restrict__ qavg, const float* __restrict__ Wq,
    const float* __restrict__ kv, float* __restrict__ obuf)
{
    __shared__ float qa[64];
    __shared__ float ql[64];
    __shared__ float hredm[4][8];
    __shared__ float hredd[4][8];
    __shared__ float maxs[8];
    __shared__ float dens[8];
    __shared__ float wred[4][64];
    const int t = threadIdx.x;
    const int r = blockIdx.x;
    if (t < 64) qa[t] = qavg[(size_t)r * 64 + t];
    __syncthreads();
    if (t < 64) {
        float a = 0.f;
        for (int i = 0; i < 64; i++) a += qa[i] * Wq[i * 64 + t];
        // q = (q_avg_sum / 2048) @ Wq * 8^-0.5
        ql[t] = a * (1.0f / 2048.0f) * 0.35355339059327373f;
    }
    __syncthreads();

    const float* kvr = kv + (size_t)r * SEQ * 16;
    float l[8][8];   // [i-th s chunk][head]
    #pragma unroll
    for (int i = 0; i < 8; i++) {
        const int s = t + i * 256;
        const float4 k0 = *(const float4*)(kvr + (size_t)s * 16);
        const float4 k1 = *(const float4*)(kvr + (size_t)s * 16 + 4);
        #pragma unroll
        for (int h = 0; h < 8; h++) {
            l[i][h] = ql[h*8+0]*k0.x + ql[h*8+1]*k0.y + ql[h*8+2]*k0.z + ql[h*8+3]*k0.w
                    + ql[h*8+4]*k1.x + ql[h*8+5]*k1.y + ql[h*8+6]*k1.z + ql[h*8+7]*k1.w;
        }
    }
    float pm[8];
    #pragma unroll
    for (int h = 0; h < 8; h++) {
        pm[h] = l[0][h];
        #pragma unroll
        for (int i = 1; i < 8; i++) pm[h] = fmaxf(pm[h], l[i][h]);
    }
    #pragma unroll
    for (int m = 1; m < 64; m <<= 1) {
        #pragma unroll
        for (int h = 0; h < 8; h++) pm[h] = fmaxf(pm[h], __shfl_xor(pm[h], m, 64));
    }
    const int wvi = t >> 6, lane = t & 63;
    if (lane == 0) {
        #pragma unroll
        for (int h = 0; h < 8; h++) hredm[wvi][h] = pm[h];
    }
    __syncthreads();
    if (t < 8) maxs[t] = fmaxf(fmaxf(hredm[0][t], hredm[1][t]), fmaxf(hredm[2][t], hredm[3][t]));
    __syncthreads();

    float pd[8] = {0,0,0,0,0,0,0,0};
    #pragma unroll
    for (int i = 0; i < 8; i++) {
        #pragma unroll
        for (int h = 0; h < 8; h++) {
            const float e = __expf(l[i][h] - maxs[h]);
            l[i][h] = e;
            pd[h] += e;
        }
    }
    #pragma unroll
    for (int m = 1; m < 64; m <<= 1) {
        #pragma unroll
        for (int h = 0; h < 8; h++) pd[h] += __shfl_xor(pd[h], m, 64);
    }
    if (lane == 0) {
        #pragma unroll
        for (int h = 0; h < 8; h++) hredd[wvi][h] = pd[h];
    }
    __syncthreads();
    if (t < 8) dens[t] = hredd[0][t] + hredd[1][t] + hredd[2][t] + hredd[3][t];

    float acc[64];
    #pragma unroll
    for (int j = 0; j < 64; j++) acc[j] = 0.f;
    #pragma unroll
    for (int i = 0; i < 8; i++) {
        const int s = t + i * 256;
        const float4 v0 = *(const float4*)(kvr + (size_t)s * 16 + 8);
        const float4 v1 = *(const float4*)(kvr + (size_t)s * 16 + 12);
        #pragma unroll
        for (int h = 0; h < 8; h++) {
            const float w = l[i][h];
            acc[h*8+0] += w*v0.x; acc[h*8+1] += w*v0.y; acc[h*8+2] += w*v0.z; acc[h*8+3] += w*v0.w;
            acc[h*8+4] += w*v1.x; acc[h*8+5] += w*v1.y; acc[h*8+6] += w*v1.z; acc[h*8+7] += w*v1.w;
        }
    }
    #pragma unroll
    for (int m = 1; m < 64; m <<= 1) {
        #pragma unroll
        for (int j = 0; j < 64; j++) acc[j] += __shfl_xor(acc[j], m, 64);
    }
    if (lane == 0) {
        #pragma unroll
        for (int j = 0; j < 64; j++) wred[wvi][j] = acc[j];
    }
    __syncthreads();
    if (t < 64)
        obuf[(size_t)r * 64 + t] = (wred[0][t] + wred[1][t] + wred[2][t] + wred[3][t]) / dens[t >> 3];
}

// ---------------- Phase 3: LN + gate GEMM + output GEMM ----------------
#define FMAROW(j, av) { acc[j][0] += (av)*bv.x; acc[j][1] += (av)*bv.y; acc[j][2] += (av)*bv.z; acc[j][3] += (av)*bv.w; }

__global__ __launch_bounds__(256) void k_phase3(
    const float* __restrict__ x, const float* __restrict__ lnw, const float* __restrict__ lnb,
    const float* __restrict__ Wg, const float* __restrict__ bg,
    const float* __restrict__ Wf, const float* __restrict__ bf,
    const float* __restrict__ obuf, float* __restrict__ out)
{
    __shared__ float buf[64 * 128];   // xn^T then tmp^T, XOR-swizzled
    __shared__ float wlds[64 * 64];   // Wg then Wf
    const int t = threadIdx.x;
    const int s = blockIdx.x;
    const int rbase = blockIdx.y * 128;

    {   // stage Wg
        const float4* src = (const float4*)Wg;
        float4* dst = (float4*)wlds;
        #pragma unroll
        for (int i = 0; i < 4; i++) dst[t + i * 256] = src[t + i * 256];
    }

    const int rl = t >> 4;
    const int c4 = t & 15;
    const float4 lw = *(const float4*)(lnw + (c4 << 2));
    const float4 lb = *(const float4*)(lnb + (c4 << 2));
    #pragma unroll
    for (int p = 0; p < 8; p++) {
        const int row = p * 16 + rl;   // 0..127
        const float4 xv = *(const float4*)(x + ((size_t)s * RDIM + rbase + row) * CDIM + (c4 << 2));
        float sum = xv.x + xv.y + xv.z + xv.w;
        float sq  = xv.x * xv.x + xv.y * xv.y + xv.z * xv.z + xv.w * xv.w;
        #pragma unroll
        for (int m = 1; m < 16; m <<= 1) {
            sum += __shfl_xor(sum, m, 16);
            sq  += __shfl_xor(sq,  m, 16);
        }
        const float mu   = sum * (1.0f / 64.0f);
        const float rstd = rsqrtf(sq * (1.0f / 64.0f) - mu * mu + 1e-5f);
        buf[XOFF(c4*4+0, row)] = (xv.x - mu) * rstd * lw.x + lb.x;
        buf[XOFF(c4*4+1, row)] = (xv.y - mu) * rstd * lw.y + lb.y;
        buf[XOFF(c4*4+2, row)] = (xv.z - mu) * rstd * lw.z + lb.z;
        buf[XOFF(c4*4+3, row)] = (xv.w - mu) * rstd * lw.w + lb.w;
    }
    __syncthreads();

    const int rt = t >> 4;   // rows 8rt..8rt+7
    const int ct = t & 15;   // cols 4ct..4ct+3
    float acc[8][4];
    #pragma unroll
    for (int j = 0; j < 8; j++) { acc[j][0]=0.f; acc[j][1]=0.f; acc[j][2]=0.f; acc[j][3]=0.f; }

    // GEMM1: g_pre = xn @ Wg
    #pragma unroll 8
    for (int k = 0; k < 64; k++) {
        const float4 bv = *(const float4*)(wlds + (k << 6) + (ct << 2));
        const float* ap = buf + ((k << 7) + ((rt ^ ((k >> 2) & 15)) << 3));
        const float4 a0 = *(const float4*)ap;
        const float4 a1 = *(const float4*)(ap + 4);
        FMAROW(0, a0.x) FMAROW(1, a0.y) FMAROW(2, a0.z) FMAROW(3, a0.w)
        FMAROW(4, a1.x) FMAROW(5, a1.y) FMAROW(6, a1.z) FMAROW(7, a1.w)
    }

    // gate + multiply by o
    const float4 bgv = *(const float4*)(bg + (ct << 2));
    #pragma unroll
    for (int j = 0; j < 8; j++) {
        const float4 ov = *(const float4*)(obuf + (size_t)(rbase + rt * 8 + j) * 64 + (ct << 2));
        acc[j][0] = ov.x * sigmoidf_(acc[j][0] + bgv.x);
        acc[j][1] = ov.y * sigmoidf_(acc[j][1] + bgv.y);
        acc[j][2] = ov.z * sigmoidf_(acc[j][2] + bgv.z);
        acc[j][3] = ov.w * sigmoidf_(acc[j][3] + bgv.w);
    }
    __syncthreads();   // everyone done reading buf (xn) and wlds (Wg)

    {   // stage Wf
        const float4* src = (const float4*)Wf;
        float4* dst = (float4*)wlds;
        #pragma unroll
        for (int i = 0; i < 4; i++) dst[t + i * 256] = src[t + i * 256];
    }
    // write tmp^T
    #pragma unroll
    for (int kk = 0; kk < 4; kk++) {
        const int col = ct * 4 + kk;
        float* p = buf + ((col << 7) + (((rt ^ ct) & 15) << 3));
        float4 w0, w1;
        w0.x = acc[0][kk]; w0.y = acc[1][kk]; w0.z = acc[2][kk]; w0.w = acc[3][kk];
        w1.x = acc[4][kk]; w1.y = acc[5][kk]; w1.z = acc[6][kk]; w1.w = acc[7][kk];
        *(float4*)p = w0;
        *((float4*)p + 1) = w1;
    }
    __syncthreads();

    #pragma unroll
    for (int j = 0; j < 8; j++) { acc[j][0]=0.f; acc[j][1]=0.f; acc[j][2]=0.f; acc[j][3]=0.f; }

    // GEMM2: out = tmp @ Wf
    #pragma unroll 8
    for (int k = 0; k < 64; k++) {
        const float4 bv = *(const float4*)(wlds + (k << 6) + (ct << 2));
        const float* ap = buf + ((k << 7) + ((rt ^ ((k >> 2) & 15)) << 3));
        const float4 a0 = *(const float4*)ap;
        const float4 a1 = *(const float4*)(ap + 4);
        FMAROW(0, a0.x) FMAROW(1, a0.y) FMAROW(2, a0.z) FMAROW(3, a0.w)
        FMAROW(4, a1.x) FMAROW(5, a1.y) FMAROW(6, a1.z) FMAROW(7, a1.w)
    }

    const float4 bfv = *(const float4*)(bf + (ct << 2));
    #pragma unroll
    for (int j = 0; j < 8; j++) {
        float4 res;
        res.x = acc[j][0] + bfv.x;
        res.y = acc[j][1] + bfv.y;
        res.z = acc[j][2] + bfv.z;
        res.w = acc[j][3] + bfv.w;
        *(float4*)(out + ((size_t)s * RDIM + rbase + rt * 8 + j) * CDIM + (ct << 2)) = res;
    }
}

extern "C" void kernel_launch(void* const* d_in, const int* in_sizes, int n_in,
                              void* d_out, int out_size, void* d_ws, size_t ws_size,
                              hipStream_t stream)
{
    const float* x   = (const float*)d_in[0];
    const float* lnw = (const float*)d_in[1];
    const float* lnb = (const float*)d_in[2];
    const float* Wq  = (const float*)d_in[3];
    const float* Wk  = (const float*)d_in[4];
    const float* Wv  = (const float*)d_in[5];
    const float* Wg  = (const float*)d_in[6];
    const float* bg  = (const float*)d_in[7];
    const float* Wf  = (const float*)d_in[8];
    const float* bf  = (const float*)d_in[9];

    float* ws    = (float*)d_ws;
    float* qpart = ws;                                   // 32*384*64   = 786432 floats
    float* qavg  = ws + 786432;                          // 384*64      = 24576
    float* obuf  = ws + 786432 + 24576;                  // 384*64      = 24576
    float* kvbuf = ws + 786432 + 24576 + 24576;          // 384*2048*16 = 12582912
    float* outp  = (float*)d_out;

    k_phase1<<<768, 256, 0, stream>>>(x, lnw, lnb, Wk, Wv, qpart, kvbuf);
    k_reduce<<<96, 256, 0, stream>>>(qpart, qavg);
    k_phase2<<<384, 256, 0, stream>>>(qavg, Wq, kvbuf, obuf);
    k_phase3<<<dim3(2048, 3), 256, 0, stream>>>(x, lnw, lnb, Wg, bg, Wf, bf, obuf, outp);
}

// Round 2
// 181.309 us; speedup vs baseline: 2.2089x; 2.2089x over previous
//
#include <hip/hip_runtime.h>

#define SEQ  2048
#define RDIM 384
#define CDIM 64

typedef __attribute__((ext_vector_type(8))) short s16x8;
typedef __attribute__((ext_vector_type(4))) float f32x4;
#define MFMA(a,b,c) __builtin_amdgcn_mfma_f32_16x16x32_bf16(a,b,c,0,0,0)

__device__ __forceinline__ unsigned short f2bf(float x) {
    union { float f; unsigned u; } a; a.f = x;
    unsigned r = a.u + 0x7fffu + ((a.u >> 16) & 1u);
    return (unsigned short)(r >> 16);
}
__device__ __forceinline__ float bf2f(unsigned u16) {
    union { unsigned u; float f; } a; a.u = u16 << 16; return a.f;
}
__device__ __forceinline__ float sigmoidf_(float z) { return 1.0f / (1.0f + __expf(-z)); }

// element offset of (row, k) in a [rows][64] bf16 tile, 8-elem-group XOR swizzle
#define SWZ(row,k) ((row)*64 + (((((k)>>3) ^ ((row)&7)))<<3) + ((k)&7))

// ---------------- prep: transposed/permuted bf16 weights (pre-swizzled) ----------------
__global__ __launch_bounds__(256) void k_prep(
    const float* __restrict__ Wk, const float* __restrict__ Wv,
    const float* __restrict__ Wg, const float* __restrict__ Wf,
    unsigned short* __restrict__ wkvt, unsigned short* __restrict__ wgt,
    unsigned short* __restrict__ wfp)
{
    const int t = threadIdx.x, b = blockIdx.x;
    if (b == 0) {
        for (int idx = t; idx < 16 * 64; idx += 256) {
            const int kc = idx >> 6, k = idx & 63;
            const float v = (kc < 8) ? Wk[k * 8 + kc] : Wv[k * 8 + (kc - 8)];
            wkvt[SWZ(kc, k)] = f2bf(v);
        }
    } else if (b == 1) {
        for (int idx = t; idx < 64 * 64; idx += 256) {
            const int col = idx >> 6, k = idx & 63;
            wgt[SWZ(col, k)] = f2bf(Wg[k * 64 + col]);
        }
    } else {
        for (int idx = t; idx < 64 * 64; idx += 256) {
            const int cout = idx >> 6, p = idx & 63;
            const int kst = p >> 5, h = (p >> 3) & 3, rr = p & 7;
            const int j = kst * 32 + (rr < 4 ? 4 * h + rr : 16 + 4 * h + (rr - 4));
            wfp[SWZ(cout, p)] = f2bf(Wf[j * 64 + cout]);
        }
    }
}

// ---------------- Phase 1: LN + q_avg partials + kv projection (MFMA) ----------------
__global__ __launch_bounds__(256) void k_phase1(
    const float* __restrict__ x, const float* __restrict__ lnw, const float* __restrict__ lnb,
    const unsigned short* __restrict__ wkvt,
    float* __restrict__ qpart, unsigned short* __restrict__ kv)
{
    __shared__ __align__(16) unsigned short xs[128 * 64];   // swizzled bf16 xn sub-tile
    __shared__ __align__(16) unsigned short wkv[16 * 64];   // pre-swizzled Wkv^T
    const int t = threadIdx.x;
    ((unsigned*)wkv)[t]       = ((const unsigned*)wkvt)[t];
    ((unsigned*)wkv)[t + 256] = ((const unsigned*)wkvt)[t + 256];

    const int rtile  = blockIdx.x % 24;
    const int schunk = blockIdx.x / 24;
    const int g  = t >> 4;      // row group (fixed r)
    const int c4 = t & 15;      // float4 column
    const int r  = rtile * 16 + g;
    const int wv = t >> 6, lane = t & 63, hi = lane >> 4, l15 = lane & 15;
    const float4 lw = *(const float4*)(lnw + (c4 << 2));
    const float4 lb = *(const float4*)(lnb + (c4 << 2));

    float qs0 = 0.f, qs1 = 0.f, qs2 = 0.f, qs3 = 0.f;
    for (int sub = 0; sub < 8; ++sub) {
        __syncthreads();   // xs free (iter0: wkv staged)
        #pragma unroll
        for (int it = 0; it < 8; ++it) {
            const int row = it * 16 + g;     // = sl*16 + rl, sl=it, rl=g
            const int s = schunk * 64 + sub * 8 + it;
            const float4 xv = *(const float4*)(x + ((size_t)s * RDIM + r) * CDIM + (c4 << 2));
            float sum = xv.x + xv.y + xv.z + xv.w;
            float sq  = xv.x * xv.x + xv.y * xv.y + xv.z * xv.z + xv.w * xv.w;
            #pragma unroll
            for (int m = 1; m < 16; m <<= 1) {
                sum += __shfl_xor(sum, m, 16);
                sq  += __shfl_xor(sq,  m, 16);
            }
            const float mu   = sum * (1.0f / 64.0f);
            const float rstd = rsqrtf(sq * (1.0f / 64.0f) - mu * mu + 1e-5f);
            const float xn0 = (xv.x - mu) * rstd * lw.x + lb.x;
            const float xn1 = (xv.y - mu) * rstd * lw.y + lb.y;
            const float xn2 = (xv.z - mu) * rstd * lw.z + lb.z;
            const float xn3 = (xv.w - mu) * rstd * lw.w + lb.w;
            qs0 += xn0; qs1 += xn1; qs2 += xn2; qs3 += xn3;
            ushort4 pk; pk.x = f2bf(xn0); pk.y = f2bf(xn1); pk.z = f2bf(xn2); pk.w = f2bf(xn3);
            *(ushort4*)&xs[row * 64 + ((((c4 >> 1) ^ (row & 7)) << 3) | ((c4 & 1) << 2))] = pk;
        }
        __syncthreads();
        // kv^T = Wkv^T @ xn^T : per wave 32 rows, 4 MFMA
        f32x4 acc0 = 0, acc1 = 0;
        #pragma unroll
        for (int kst = 0; kst < 2; ++kst) {
            const int kg = (kst * 4 + hi);
            const s16x8 a = *(const s16x8*)&wkv[l15 * 64 + ((kg ^ (l15 & 7)) << 3)];
            const int row0 = wv * 32 + l15;
            const s16x8 b0 = *(const s16x8*)&xs[row0 * 64 + ((kg ^ (l15 & 7)) << 3)];
            const s16x8 b1 = *(const s16x8*)&xs[(row0 + 16) * 64 + ((kg ^ (l15 & 7)) << 3)];
            acc0 = MFMA(a, b0, acc0);
            acc1 = MFMA(a, b1, acc1);
        }
        #pragma unroll
        for (int ni = 0; ni < 2; ++ni) {
            const f32x4 av = ni ? acc1 : acc0;
            const int srow = schunk * 64 + sub * 8 + 2 * wv + ni;
            const int rrow = rtile * 16 + l15;
            ushort4 pk; pk.x = f2bf(av[0]); pk.y = f2bf(av[1]); pk.z = f2bf(av[2]); pk.w = f2bf(av[3]);
            *(ushort4*)(kv + ((size_t)srow * RDIM + rrow) * 16 + (hi << 2)) = pk;
        }
    }
    float4 q4; q4.x = qs0; q4.y = qs1; q4.z = qs2; q4.w = qs3;
    *(float4*)(qpart + ((size_t)schunk * RDIM + r) * CDIM + (c4 << 2)) = q4;
}

// ---------------- Phase 2: qpart reduce + q + logits + softmax + o ----------------
__global__ __launch_bounds__(256) void k_phase2(
    const float* __restrict__ qpart, const float* __restrict__ Wq,
    const unsigned short* __restrict__ kv, float* __restrict__ obuf)
{
    __shared__ float qa[64];
    __shared__ float ql[64];
    __shared__ float hredm[4][8];
    __shared__ float hredd[4][8];
    __shared__ float maxs[8];
    __shared__ float dens[8];
    __shared__ float wred[4][64];
    const int t = threadIdx.x;
    const int r = (blockIdx.x & 7) * 48 + (blockIdx.x >> 3);   // XCD-chunked: adjacent r share L2
    if (t < 64) {
        float ssum = 0.f;
        #pragma unroll
        for (int ch = 0; ch < 32; ch++) ssum += qpart[(size_t)ch * (RDIM * CDIM) + r * 64 + t];
        qa[t] = ssum;
    }
    __syncthreads();
    if (t < 64) {
        float a = 0.f;
        for (int i = 0; i < 64; i++) a += qa[i] * Wq[i * 64 + t];
        ql[t] = a * (1.0f / 2048.0f) * 0.35355339059327373f;
    }
    __syncthreads();

    const unsigned short* kvr = kv + (size_t)r * 16;
    float l[8][8];
    #pragma unroll
    for (int i = 0; i < 8; i++) {
        const int s = t + i * 256;
        const uint4 ku = *(const uint4*)(kvr + (size_t)s * (RDIM * 16));
        float kf[8];
        kf[0] = bf2f(ku.x & 0xffff); kf[1] = bf2f(ku.x >> 16);
        kf[2] = bf2f(ku.y & 0xffff); kf[3] = bf2f(ku.y >> 16);
        kf[4] = bf2f(ku.z & 0xffff); kf[5] = bf2f(ku.z >> 16);
        kf[6] = bf2f(ku.w & 0xffff); kf[7] = bf2f(ku.w >> 16);
        #pragma unroll
        for (int h = 0; h < 8; h++) {
            float a = 0.f;
            #pragma unroll
            for (int c = 0; c < 8; c++) a += ql[h * 8 + c] * kf[c];
            l[i][h] = a;
        }
    }
    float pm[8];
    #pragma unroll
    for (int h = 0; h < 8; h++) {
        pm[h] = l[0][h];
        #pragma unroll
        for (int i = 1; i < 8; i++) pm[h] = fmaxf(pm[h], l[i][h]);
    }
    #pragma unroll
    for (int m = 1; m < 64; m <<= 1) {
        #pragma unroll
        for (int h = 0; h < 8; h++) pm[h] = fmaxf(pm[h], __shfl_xor(pm[h], m, 64));
    }
    const int wvi = t >> 6, lane = t & 63;
    if (lane == 0) {
        #pragma unroll
        for (int h = 0; h < 8; h++) hredm[wvi][h] = pm[h];
    }
    __syncthreads();
    if (t < 8) maxs[t] = fmaxf(fmaxf(hredm[0][t], hredm[1][t]), fmaxf(hredm[2][t], hredm[3][t]));
    __syncthreads();

    float pd[8] = {0,0,0,0,0,0,0,0};
    #pragma unroll
    for (int i = 0; i < 8; i++) {
        #pragma unroll
        for (int h = 0; h < 8; h++) {
            const float e = __expf(l[i][h] - maxs[h]);
            l[i][h] = e;
            pd[h] += e;
        }
    }
    #pragma unroll
    for (int m = 1; m < 64; m <<= 1) {
        #pragma unroll
        for (int h = 0; h < 8; h++) pd[h] += __shfl_xor(pd[h], m, 64);
    }
    if (lane == 0) {
        #pragma unroll
        for (int h = 0; h < 8; h++) hredd[wvi][h] = pd[h];
    }
    __syncthreads();
    if (t < 8) dens[t] = hredd[0][t] + hredd[1][t] + hredd[2][t] + hredd[3][t];

    float acc[64];
    #pragma unroll
    for (int j = 0; j < 64; j++) acc[j] = 0.f;
    #pragma unroll
    for (int i = 0; i < 8; i++) {
        const int s = t + i * 256;
        const uint4 vu = *(const uint4*)(kvr + (size_t)s * (RDIM * 16) + 8);
        float vf[8];
        vf[0] = bf2f(vu.x & 0xffff); vf[1] = bf2f(vu.x >> 16);
        vf[2] = bf2f(vu.y & 0xffff); vf[3] = bf2f(vu.y >> 16);
        vf[4] = bf2f(vu.z & 0xffff); vf[5] = bf2f(vu.z >> 16);
        vf[6] = bf2f(vu.w & 0xffff); vf[7] = bf2f(vu.w >> 16);
        #pragma unroll
        for (int h = 0; h < 8; h++) {
            const float w = l[i][h];
            #pragma unroll
            for (int c = 0; c < 8; c++) acc[h * 8 + c] += w * vf[c];
        }
    }
    #pragma unroll
    for (int m = 1; m < 64; m <<= 1) {
        #pragma unroll
        for (int j = 0; j < 64; j++) acc[j] += __shfl_xor(acc[j], m, 64);
    }
    if (lane == 0) {
        #pragma unroll
        for (int j = 0; j < 64; j++) wred[wvi][j] = acc[j];
    }
    __syncthreads();
    if (t < 64)
        obuf[(size_t)r * 64 + t] = (wred[0][t] + wred[1][t] + wred[2][t] + wred[3][t]) / dens[t >> 3];
}

// ---------------- Phase 3: LN + MFMA gate GEMM -> in-reg epilogue -> MFMA out GEMM ----------------
__global__ __launch_bounds__(256) void k_phase3(
    const float* __restrict__ x, const float* __restrict__ lnw, const float* __restrict__ lnb,
    const unsigned short* __restrict__ wgt, const unsigned short* __restrict__ wfp,
    const float* __restrict__ bg, const float* __restrict__ bf_,
    const float* __restrict__ obuf, float* __restrict__ out)
{
    __shared__ __align__(16) unsigned short xs[128 * 64];     // swizzled bf16 xn tile
    __shared__ __align__(16) unsigned short wg[64 * 64];      // pre-swizzled Wg^T
    __shared__ __align__(16) unsigned short wf[64 * 64];      // pre-swizzled+permuted Wf
    __shared__ __align__(16) unsigned short olds[128 * 68];   // o tile bf16, padded stride
    __shared__ __align__(16) float bgl[64];
    __shared__ __align__(16) float bfl[64];
    const int t = threadIdx.x;
    const int rtile = blockIdx.x % 3;
    const int sb    = blockIdx.x / 3;
    const int rbase = rtile * 128;

    #pragma unroll
    for (int i = 0; i < 8; ++i) ((unsigned*)wg)[t + i * 256] = ((const unsigned*)wgt)[t + i * 256];
    #pragma unroll
    for (int i = 0; i < 8; ++i) ((unsigned*)wf)[t + i * 256] = ((const unsigned*)wfp)[t + i * 256];
    if (t < 64) { bgl[t] = bg[t]; bfl[t] = bf_[t]; }
    #pragma unroll
    for (int i = 0; i < 8; ++i) {
        const int idx = t + i * 256;
        const int row = idx >> 4, c = idx & 15;
        const float4 ov = *(const float4*)(obuf + (size_t)(rbase + row) * 64 + (c << 2));
        ushort4 pk; pk.x = f2bf(ov.x); pk.y = f2bf(ov.y); pk.z = f2bf(ov.z); pk.w = f2bf(ov.w);
        *(ushort4*)&olds[row * 68 + (c << 2)] = pk;
    }

    const int g = t >> 4, c4 = t & 15;
    const float4 lw = *(const float4*)(lnw + (c4 << 2));
    const float4 lb = *(const float4*)(lnb + (c4 << 2));
    const int wv = t >> 6, lane = t & 63, hi = lane >> 4, l15 = lane & 15;
    float bfv[4];

    for (int si = 0; si < 4; ++si) {
        const int s = sb * 4 + si;
        __syncthreads();   // xs free (iter0: also covers weight/o staging)
        #pragma unroll
        for (int it = 0; it < 8; ++it) {
            const int row = it * 16 + g;
            const float4 xv = *(const float4*)(x + ((size_t)s * RDIM + rbase + row) * CDIM + (c4 << 2));
            float sum = xv.x + xv.y + xv.z + xv.w;
            float sq  = xv.x * xv.x + xv.y * xv.y + xv.z * xv.z + xv.w * xv.w;
            #pragma unroll
            for (int m = 1; m < 16; m <<= 1) {
                sum += __shfl_xor(sum, m, 16);
                sq  += __shfl_xor(sq,  m, 16);
            }
            const float mu   = sum * (1.0f / 64.0f);
            const float rstd = rsqrtf(sq * (1.0f / 64.0f) - mu * mu + 1e-5f);
            ushort4 pk;
            pk.x = f2bf((xv.x - mu) * rstd * lw.x + lb.x);
            pk.y = f2bf((xv.y - mu) * rstd * lw.y + lb.y);
            pk.z = f2bf((xv.z - mu) * rstd * lw.z + lb.z);
            pk.w = f2bf((xv.w - mu) * rstd * lw.w + lb.w);
            *(ushort4*)&xs[row * 64 + ((((c4 >> 1) ^ (row & 7)) << 3) | ((c4 & 1) << 2))] = pk;
        }
        __syncthreads();

        // GEMM1: z^T = Wg^T @ xn^T  (M=64 cols, N=128 rows, K=64)
        f32x4 acc1[4][2];
        #pragma unroll
        for (int mi = 0; mi < 4; ++mi) { acc1[mi][0] = 0; acc1[mi][1] = 0; }
        #pragma unroll
        for (int kst = 0; kst < 2; ++kst) {
            const int kg = kst * 4 + hi;
            s16x8 bfr[2];
            #pragma unroll
            for (int ni = 0; ni < 2; ++ni) {
                const int row = wv * 32 + ni * 16 + l15;
                bfr[ni] = *(const s16x8*)&xs[row * 64 + ((kg ^ (l15 & 7)) << 3)];
            }
            #pragma unroll
            for (int mi = 0; mi < 4; ++mi) {
                const int col = mi * 16 + l15;
                const s16x8 afr = *(const s16x8*)&wg[col * 64 + ((kg ^ (l15 & 7)) << 3)];
                acc1[mi][0] = MFMA(afr, bfr[0], acc1[mi][0]);
                acc1[mi][1] = MFMA(afr, bfr[1], acc1[mi][1]);
            }
        }

        // Epilogue 1 (in-register): gate = sigmoid(z + bg), t = gate * o -> A2 frags
        s16x8 a2[2][2];
        #pragma unroll
        for (int ni = 0; ni < 2; ++ni) {
            const int row = wv * 32 + ni * 16 + l15;
            #pragma unroll
            for (int mi = 0; mi < 4; ++mi) {
                const int jb = mi * 16 + (hi << 2);
                const ushort4 ou = *(const ushort4*)&olds[row * 68 + jb];
                float o4[4];
                o4[0] = bf2f(ou.x); o4[1] = bf2f(ou.y); o4[2] = bf2f(ou.z); o4[3] = bf2f(ou.w);
                const f32x4 bg4 = *(const f32x4*)&bgl[jb];
                #pragma unroll
                for (int rg = 0; rg < 4; ++rg) {
                    const float z = acc1[mi][ni][rg] + bg4[rg];
                    const float tv = sigmoidf_(z) * o4[rg];
                    a2[ni][mi >> 1][((mi & 1) << 2) + rg] = (short)f2bf(tv);
                }
            }
        }

        // GEMM2: out = t @ Wf  (M=128 rows, N=64 couts, K=64 j, pre-permuted Wf)
        f32x4 acc2[2][4];
        #pragma unroll
        for (int ni = 0; ni < 2; ++ni)
            #pragma unroll
            for (int ci = 0; ci < 4; ++ci) acc2[ni][ci] = 0;
        #pragma unroll
        for (int kst = 0; kst < 2; ++kst) {
            const int kg = kst * 4 + hi;
            #pragma unroll
            for (int ci = 0; ci < 4; ++ci) {
                const int co = ci * 16 + l15;
                const s16x8 bfr = *(const s16x8*)&wf[co * 64 + ((kg ^ (l15 & 7)) << 3)];
                acc2[0][ci] = MFMA(a2[0][kst], bfr, acc2[0][ci]);
                acc2[1][ci] = MFMA(a2[1][kst], bfr, acc2[1][ci]);
            }
        }

        #pragma unroll
        for (int ci = 0; ci < 4; ++ci) bfv[ci] = bfl[ci * 16 + l15];
        #pragma unroll
        for (int ni = 0; ni < 2; ++ni) {
            #pragma unroll
            for (int rg = 0; rg < 4; ++rg) {
                const int row = wv * 32 + ni * 16 + (hi << 2) + rg;
                float* op = out + ((size_t)s * RDIM + rbase + row) * CDIM + l15;
                #pragma unroll
                for (int ci = 0; ci < 4; ++ci)
                    op[ci * 16] = acc2[ni][ci][rg] + bfv[ci];
            }
        }
    }
}

extern "C" void kernel_launch(void* const* d_in, const int* in_sizes, int n_in,
                              void* d_out, int out_size, void* d_ws, size_t ws_size,
                              hipStream_t stream)
{
    const float* x   = (const float*)d_in[0];
    const float* lnw = (const float*)d_in[1];
    const float* lnb = (const float*)d_in[2];
    const float* Wq  = (const float*)d_in[3];
    const float* Wk  = (const float*)d_in[4];
    const float* Wv  = (const float*)d_in[5];
    const float* Wg  = (const float*)d_in[6];
    const float* bg  = (const float*)d_in[7];
    const float* Wf  = (const float*)d_in[8];
    const float* bf  = (const float*)d_in[9];

    char* ws = (char*)d_ws;
    float* qpart         = (float*)ws;                       // 32*384*64 f32  = 3145728 B
    float* obuf          = (float*)(ws + 3145728);           // 384*64 f32     = 98304 B
    unsigned short* kv   = (unsigned short*)(ws + 3244032);  // 2048*384*16 bf = 25165824 B
    unsigned short* wkvt = (unsigned short*)(ws + 28409856); // 16*64
    unsigned short* wgt  = wkvt + 1024;                      // 64*64
    unsigned short* wfp  = wgt + 4096;                       // 64*64

    float* outp = (float*)d_out;

    k_prep<<<3, 256, 0, stream>>>(Wk, Wv, Wg, Wf, wkvt, wgt, wfp);
    k_phase1<<<768, 256, 0, stream>>>(x, lnw, lnb, wkvt, qpart, kv);
    k_phase2<<<384, 256, 0, stream>>>(qpart, Wq, kv, obuf);
    k_phase3<<<1536, 256, 0, stream>>>(x, lnw, lnb, wgt, wfp, bg, bf, obuf, outp);
}

// Round 3
// 171.378 us; speedup vs baseline: 2.3369x; 1.0579x over previous
//
#include <hip/hip_runtime.h>

#define SEQ  2048
#define RDIM 384
#define CDIM 64

typedef __attribute__((ext_vector_type(8))) short s16x8;
typedef __attribute__((ext_vector_type(4))) float f32x4;
#define MFMA(a,b,c) __builtin_amdgcn_mfma_f32_16x16x32_bf16(a,b,c,0,0,0)

__device__ __forceinline__ unsigned short f2bf(float x) {
    union { float f; unsigned u; } a; a.f = x;
    unsigned r = a.u + 0x7fffu + ((a.u >> 16) & 1u);
    return (unsigned short)(r >> 16);
}
__device__ __forceinline__ unsigned pack2(float lo, float hi) {
    return (unsigned)f2bf(lo) | ((unsigned)f2bf(hi) << 16);
}
__device__ __forceinline__ float bf2f(unsigned u16) {
    union { unsigned u; float f; } a; a.u = u16 << 16; return a.f;
}
__device__ __forceinline__ float uaf(unsigned u) {
    union { unsigned u; float f; } a; a.u = u; return a.f;
}

// element offset of (row, k) in a [rows][64] bf16 tile, 8-elem-group XOR swizzle
#define SWZ(row,k) ((row)*64 + (((((k)>>3) ^ ((row)&7)))<<3) + ((k)&7))

// ---------------- prep: LN-folded transposed/permuted bf16 weights ----------------
__global__ __launch_bounds__(256) void k_prep(
    const float* __restrict__ Wk, const float* __restrict__ Wv,
    const float* __restrict__ Wg, const float* __restrict__ Wf,
    const float* __restrict__ lnw, const float* __restrict__ lnb,
    const float* __restrict__ bg,
    unsigned short* __restrict__ wkvt, unsigned short* __restrict__ wgt,
    unsigned short* __restrict__ wfp, float* __restrict__ kvbias,
    float* __restrict__ bgp)
{
    const int t = threadIdx.x, b = blockIdx.x;
    if (b == 0) {
        for (int idx = t; idx < 16 * 64; idx += 256) {
            const int kc = idx >> 6, k = idx & 63;
            const float v = lnw[k] * ((kc < 8) ? Wk[k * 8 + kc] : Wv[k * 8 + (kc - 8)]);
            wkvt[SWZ(kc, k)] = f2bf(v);
        }
        if (t < 16) {
            float a = 0.f;
            for (int k = 0; k < 64; k++)
                a += lnb[k] * ((t < 8) ? Wk[k * 8 + t] : Wv[k * 8 + (t - 8)]);
            kvbias[t] = a;
        }
    } else if (b == 1) {
        for (int idx = t; idx < 64 * 64; idx += 256) {
            const int col = idx >> 6, k = idx & 63;
            wgt[SWZ(col, k)] = f2bf(lnw[k] * Wg[k * 64 + col]);
        }
        if (t < 64) {
            float a = bg[t];
            for (int k = 0; k < 64; k++) a += lnb[k] * Wg[k * 64 + t];
            bgp[t] = a;
        }
    } else {
        for (int idx = t; idx < 64 * 64; idx += 256) {
            const int cout = idx >> 6, p = idx & 63;
            const int kst = p >> 5, h = (p >> 3) & 3, rr = p & 7;
            const int j = kst * 32 + (rr < 4 ? 4 * h + rr : 16 + 4 * h + (rr - 4));
            wfp[SWZ(cout, p)] = f2bf(Wf[j * 64 + cout]);
        }
    }
}

// ---------------- Phase 1: LN(xhat) + q_avg partials + kv projection (MFMA) ----------------
__global__ __launch_bounds__(256) void k_phase1(
    const float* __restrict__ x, const unsigned short* __restrict__ wkvt,
    float* __restrict__ qpart, unsigned short* __restrict__ kv)
{
    __shared__ __align__(16) unsigned short xs[128 * 64];   // swizzled bf16 xhat sub-tile
    __shared__ __align__(16) unsigned short wkv[16 * 64];   // pre-swizzled LN-folded Wkv^T
    const int t = threadIdx.x;
    ((unsigned*)wkv)[t]       = ((const unsigned*)wkvt)[t];
    ((unsigned*)wkv)[t + 256] = ((const unsigned*)wkvt)[t + 256];

    const int rtile  = blockIdx.x % 24;
    const int schunk = blockIdx.x / 24;
    const int g  = t >> 4;      // row group (fixed r)
    const int c4 = t & 15;      // float4 column
    const int r = rtile * 16 + g;
    const int wv = t >> 6, lane = t & 63, hi = lane >> 4, l15 = lane & 15;

    float qs0 = 0.f, qs1 = 0.f, qs2 = 0.f, qs3 = 0.f;
    for (int sub = 0; sub < 8; ++sub) {
        __syncthreads();   // xs free (iter0: wkv staged)
        #pragma unroll
        for (int it = 0; it < 8; ++it) {
            const int row = it * 16 + g;
            const int s = schunk * 64 + sub * 8 + it;
            const float4 xv = *(const float4*)(x + ((size_t)s * RDIM + r) * CDIM + (c4 << 2));
            float sum = xv.x + xv.y + xv.z + xv.w;
            float sq  = xv.x * xv.x + xv.y * xv.y + xv.z * xv.z + xv.w * xv.w;
            #pragma unroll
            for (int m = 1; m < 16; m <<= 1) {
                sum += __shfl_xor(sum, m, 16);
                sq  += __shfl_xor(sq,  m, 16);
            }
            const float mu   = sum * (1.0f / 64.0f);
            const float rstd = rsqrtf(sq * (1.0f / 64.0f) - mu * mu + 1e-5f);
            const float xn0 = (xv.x - mu) * rstd;
            const float xn1 = (xv.y - mu) * rstd;
            const float xn2 = (xv.z - mu) * rstd;
            const float xn3 = (xv.w - mu) * rstd;
            qs0 += xn0; qs1 += xn1; qs2 += xn2; qs3 += xn3;
            ushort4 pk; pk.x = f2bf(xn0); pk.y = f2bf(xn1); pk.z = f2bf(xn2); pk.w = f2bf(xn3);
            *(ushort4*)&xs[row * 64 + ((((c4 >> 1) ^ (row & 7)) << 3) | ((c4 & 1) << 2))] = pk;
        }
        __syncthreads();
        // kv^T = Wkv'^T @ xhat^T : per wave 32 rows, 4 MFMA
        f32x4 acc0 = 0, acc1 = 0;
        #pragma unroll
        for (int kst = 0; kst < 2; ++kst) {
            const int kg = (kst * 4 + hi);
            const s16x8 a = *(const s16x8*)&wkv[l15 * 64 + ((kg ^ (l15 & 7)) << 3)];
            const int row0 = wv * 32 + l15;
            const s16x8 b0 = *(const s16x8*)&xs[row0 * 64 + ((kg ^ (l15 & 7)) << 3)];
            const s16x8 b1 = *(const s16x8*)&xs[(row0 + 16) * 64 + ((kg ^ (l15 & 7)) << 3)];
            acc0 = MFMA(a, b0, acc0);
            acc1 = MFMA(a, b1, acc1);
        }
        #pragma unroll
        for (int ni = 0; ni < 2; ++ni) {
            const f32x4 av = ni ? acc1 : acc0;
            const int srow = schunk * 64 + sub * 8 + 2 * wv + ni;
            const int rrow = rtile * 16 + l15;
            ushort4 pk; pk.x = f2bf(av[0]); pk.y = f2bf(av[1]); pk.z = f2bf(av[2]); pk.w = f2bf(av[3]);
            *(ushort4*)(kv + ((size_t)rrow * SEQ + srow) * 16 + (hi << 2)) = pk;
        }
    }
    float4 q4; q4.x = qs0; q4.y = qs1; q4.z = qs2; q4.w = qs3;
    *(float4*)(qpart + ((size_t)schunk * RDIM + r) * CDIM + (c4 << 2)) = q4;
}

// ---------------- Phase 2a: q + logits(no-max) + partial den/num per s-half ----------------
__global__ __launch_bounds__(256) void k_phase2a(
    const float* __restrict__ qpart, const float* __restrict__ Wq,
    const float* __restrict__ lnw, const float* __restrict__ lnb,
    const float* __restrict__ kvbias, const unsigned short* __restrict__ kv,
    float* __restrict__ num, float* __restrict__ den)
{
    __shared__ float qa[64];
    __shared__ float ql[64];
    __shared__ float lbias[8];
    __shared__ float hredd[4][8];
    __shared__ float wred[4][64];
    const int t = threadIdx.x;
    const int r = blockIdx.x >> 1;
    const int half = blockIdx.x & 1;
    if (t < 64) {
        float ssum = 0.f;
        #pragma unroll
        for (int ch = 0; ch < 32; ch++) ssum += qpart[(size_t)ch * (RDIM * CDIM) + r * 64 + t];
        qa[t] = ssum;
    }
    __syncthreads();
    if (t < 64) {
        float a = 0.f;
        for (int i = 0; i < 64; i++)
            a += (qa[i] * (1.0f / 2048.0f) * lnw[i] + lnb[i]) * Wq[i * 64 + t];
        ql[t] = a * 0.35355339059327373f;
    }
    __syncthreads();
    if (t < 8) {
        float a = 0.f;
        #pragma unroll
        for (int c = 0; c < 8; c++) a += ql[t * 8 + c] * kvbias[c];
        lbias[t] = a;
    }
    __syncthreads();

    const unsigned short* kvr = kv + (size_t)r * (SEQ * 16);
    float acc[64];
    float pd[8];
    #pragma unroll
    for (int j = 0; j < 64; j++) acc[j] = 0.f;
    #pragma unroll
    for (int h = 0; h < 8; h++) pd[h] = 0.f;

    #pragma unroll
    for (int i = 0; i < 4; i++) {
        const int s = half * 1024 + i * 256 + t;
        const uint4 ku = *(const uint4*)(kvr + (size_t)s * 16);
        const uint4 vu = *(const uint4*)(kvr + (size_t)s * 16 + 8);
        float kf[8], vf[8];
        kf[0] = bf2f(ku.x & 0xffff); kf[1] = bf2f(ku.x >> 16);
        kf[2] = bf2f(ku.y & 0xffff); kf[3] = bf2f(ku.y >> 16);
        kf[4] = bf2f(ku.z & 0xffff); kf[5] = bf2f(ku.z >> 16);
        kf[6] = bf2f(ku.w & 0xffff); kf[7] = bf2f(ku.w >> 16);
        vf[0] = bf2f(vu.x & 0xffff); vf[1] = bf2f(vu.x >> 16);
        vf[2] = bf2f(vu.y & 0xffff); vf[3] = bf2f(vu.y >> 16);
        vf[4] = bf2f(vu.z & 0xffff); vf[5] = bf2f(vu.z >> 16);
        vf[6] = bf2f(vu.w & 0xffff); vf[7] = bf2f(vu.w >> 16);
        #pragma unroll
        for (int h = 0; h < 8; h++) {
            float a = lbias[h];
            #pragma unroll
            for (int c = 0; c < 8; c++) a += ql[h * 8 + c] * kf[c];
            const float e = __expf(a);   // |logit| << 1, no max needed
            pd[h] += e;
            #pragma unroll
            for (int c = 0; c < 8; c++) acc[h * 8 + c] += e * vf[c];
        }
    }
    #pragma unroll
    for (int m = 1; m < 64; m <<= 1) {
        #pragma unroll
        for (int j = 0; j < 64; j++) acc[j] += __shfl_xor(acc[j], m, 64);
        #pragma unroll
        for (int h = 0; h < 8; h++) pd[h] += __shfl_xor(pd[h], m, 64);
    }
    const int wvi = t >> 6, lane = t & 63;
    if (lane == 0) {
        #pragma unroll
        for (int j = 0; j < 64; j++) wred[wvi][j] = acc[j];
        #pragma unroll
        for (int h = 0; h < 8; h++) hredd[wvi][h] = pd[h];
    }
    __syncthreads();
    if (t < 64)
        num[(size_t)(half * RDIM + r) * 64 + t] = wred[0][t] + wred[1][t] + wred[2][t] + wred[3][t];
    if (t < 8)
        den[(size_t)(half * RDIM + r) * 8 + t] = hredd[0][t] + hredd[1][t] + hredd[2][t] + hredd[3][t];
}

// ---------------- Phase 2b: merge halves + pack o into phase3 fragment image ----------------
__global__ __launch_bounds__(256) void k_phase2b(
    const float* __restrict__ num, const float* __restrict__ den,
    const float* __restrict__ kvbias, unsigned short* __restrict__ ofimg)
{
    const int idx = blockIdx.x * 256 + threadIdx.x;   // 0..24575
    const int r = idx >> 6, c = idx & 63;
    const float n = num[idx] + num[RDIM * 64 + idx];
    const float d = den[r * 8 + (c >> 3)] + den[(RDIM + r) * 8 + (c >> 3)];
    const float o = n / d + kvbias[8 + (c & 7)];
    const int rt = r >> 7, row = r & 127;
    const int wv = row >> 5, ni = (row >> 4) & 1, l15 = row & 15;
    const int mi = c >> 4, hi = (c >> 2) & 3, rg = c & 3;
    const int tt = wv * 64 + hi * 16 + l15;
    const int slot = ni * 16 + mi * 4 + rg;
    ofimg[((rt * 256 + tt) << 5) + slot] = f2bf(o);
}

// ---------------- Phase 3: LN + gate GEMM -> reg epilogue -> out GEMM (pipelined) ----------------
__global__ __launch_bounds__(256, 3) void k_phase3(
    const float* __restrict__ x,
    const unsigned short* __restrict__ wgt, const unsigned short* __restrict__ wfp,
    const float* __restrict__ bgp, const float* __restrict__ bf_,
    const unsigned short* __restrict__ ofimg, float* __restrict__ out)
{
    __shared__ __align__(16) unsigned short xs[2][128 * 64];  // dbuf swizzled bf16 xhat
    __shared__ __align__(16) unsigned short wg[64 * 64];      // pre-swizzled LN-folded Wg^T
    __shared__ __align__(16) unsigned short wf[64 * 64];      // pre-swizzled+permuted Wf
    const int t = threadIdx.x;
    const int rt = blockIdx.x % 3;
    const int sb = blockIdx.x / 3;
    const int rbase = rt * 128;

    #pragma unroll
    for (int i = 0; i < 8; ++i) ((unsigned*)wg)[t + i * 256] = ((const unsigned*)wgt)[t + i * 256];
    #pragma unroll
    for (int i = 0; i < 8; ++i) ((unsigned*)wf)[t + i * 256] = ((const unsigned*)wfp)[t + i * 256];

    const int wv = t >> 6, lane = t & 63, hi = lane >> 4, l15 = lane & 15;

    unsigned opk[16];   // o fragments, packed bf16 pairs (slot 2i | 2i+1)
    {
        const unsigned* osrc = (const unsigned*)ofimg + (size_t)(rt * 256 + t) * 16;
        #pragma unroll
        for (int i = 0; i < 16; ++i) opk[i] = osrc[i];
    }
    float bgf[4][4], bff[4][4];
    #pragma unroll
    for (int mi = 0; mi < 4; ++mi) *(float4*)bgf[mi] = *(const float4*)(bgp + mi * 16 + hi * 4);
    #pragma unroll
    for (int ci = 0; ci < 4; ++ci) *(float4*)bff[ci] = *(const float4*)(bf_ + ci * 16 + hi * 4);

    const int li = t & 3, p = t >> 2;
    float4 xv[2][4];
    {   // preload si = 0
        const int s0 = sb * 8;
        #pragma unroll
        for (int k = 0; k < 2; ++k) {
            const float* xp = x + ((size_t)s0 * RDIM + rbase + k * 64 + p) * CDIM + li * 16;
            #pragma unroll
            for (int j = 0; j < 4; ++j) xv[k][j] = *(const float4*)(xp + j * 4);
        }
    }

    for (int si = 0; si < 8; ++si) {
        const int s = sb * 8 + si;
        unsigned short* xb = xs[si & 1];
        // ---- LN (pure xhat) + pack + swizzled LDS store ----
        #pragma unroll
        for (int k = 0; k < 2; ++k) {
            const int row = k * 64 + p;
            float sum = 0.f, sq = 0.f;
            #pragma unroll
            for (int j = 0; j < 4; ++j) {
                sum += xv[k][j].x + xv[k][j].y + xv[k][j].z + xv[k][j].w;
                sq  += xv[k][j].x * xv[k][j].x + xv[k][j].y * xv[k][j].y
                     + xv[k][j].z * xv[k][j].z + xv[k][j].w * xv[k][j].w;
            }
            sum += __shfl_xor(sum, 1, 4); sum += __shfl_xor(sum, 2, 4);
            sq  += __shfl_xor(sq,  1, 4); sq  += __shfl_xor(sq,  2, 4);
            const float mu   = sum * (1.0f / 64.0f);
            const float rstd = rsqrtf(sq * (1.0f / 64.0f) - mu * mu + 1e-5f);
            uint4 w0, w1;
            w0.x = pack2((xv[k][0].x - mu) * rstd, (xv[k][0].y - mu) * rstd);
            w0.y = pack2((xv[k][0].z - mu) * rstd, (xv[k][0].w - mu) * rstd);
            w0.z = pack2((xv[k][1].x - mu) * rstd, (xv[k][1].y - mu) * rstd);
            w0.w = pack2((xv[k][1].z - mu) * rstd, (xv[k][1].w - mu) * rstd);
            w1.x = pack2((xv[k][2].x - mu) * rstd, (xv[k][2].y - mu) * rstd);
            w1.y = pack2((xv[k][2].z - mu) * rstd, (xv[k][2].w - mu) * rstd);
            w1.z = pack2((xv[k][3].x - mu) * rstd, (xv[k][3].y - mu) * rstd);
            w1.w = pack2((xv[k][3].z - mu) * rstd, (xv[k][3].w - mu) * rstd);
            *(uint4*)&xb[row * 64 + (((2 * li)     ^ (row & 7)) << 3)] = w0;
            *(uint4*)&xb[row * 64 + (((2 * li + 1) ^ (row & 7)) << 3)] = w1;
        }
        // ---- prefetch next tile: stays in flight across the barrier ----
        if (si < 7) {
            const int sn = s + 1;
            #pragma unroll
            for (int k = 0; k < 2; ++k) {
                const float* xp = x + ((size_t)sn * RDIM + rbase + k * 64 + p) * CDIM + li * 16;
                #pragma unroll
                for (int j = 0; j < 4; ++j) xv[k][j] = *(const float4*)(xp + j * 4);
            }
        }
        asm volatile("s_waitcnt lgkmcnt(0)" ::: "memory");   // LDS writes visible; vmcnt NOT drained
        __builtin_amdgcn_s_barrier();
        asm volatile("" ::: "memory");

        // ---- GEMM1: z^T = Wg'^T @ xhat^T ----
        f32x4 acc1[4][2];
        #pragma unroll
        for (int mi = 0; mi < 4; ++mi) { acc1[mi][0] = 0; acc1[mi][1] = 0; }
        #pragma unroll
        for (int kst = 0; kst < 2; ++kst) {
            const int swz = (((kst * 4 + hi) ^ (l15 & 7)) << 3);
            const s16x8 bfr0 = *(const s16x8*)&xb[(wv * 32 + l15) * 64 + swz];
            const s16x8 bfr1 = *(const s16x8*)&xb[(wv * 32 + 16 + l15) * 64 + swz];
            #pragma unroll
            for (int mi = 0; mi < 4; ++mi) {
                const s16x8 afr = *(const s16x8*)&wg[(mi * 16 + l15) * 64 + swz];
                acc1[mi][0] = MFMA(afr, bfr0, acc1[mi][0]);
                acc1[mi][1] = MFMA(afr, bfr1, acc1[mi][1]);
            }
        }
        // ---- epilogue in registers: t = sigmoid(z + bg') * o ----
        s16x8 a2[2][2];
        #pragma unroll
        for (int ni = 0; ni < 2; ++ni) {
            #pragma unroll
            for (int mi = 0; mi < 4; ++mi) {
                #pragma unroll
                for (int rg = 0; rg < 4; ++rg) {
                    const int slot = ni * 16 + mi * 4 + rg;
                    const unsigned u = opk[slot >> 1];
                    const float of = uaf((slot & 1) ? (u & 0xffff0000u) : (u << 16));
                    const float z = acc1[mi][ni][rg] + bgf[mi][rg];
                    const float tv = of / (1.0f + __expf(-z));
                    a2[ni][mi >> 1][((mi & 1) << 2) + rg] = (short)f2bf(tv);
                }
            }
        }
        // ---- GEMM2 (swapped operands): D[cout][row] ----
        f32x4 acc2[2][4];
        #pragma unroll
        for (int ni = 0; ni < 2; ++ni)
            #pragma unroll
            for (int ci = 0; ci < 4; ++ci) acc2[ni][ci] = 0;
        #pragma unroll
        for (int kst = 0; kst < 2; ++kst) {
            const int swz = (((kst * 4 + hi) ^ (l15 & 7)) << 3);
            #pragma unroll
            for (int ci = 0; ci < 4; ++ci) {
                const s16x8 wffr = *(const s16x8*)&wf[(ci * 16 + l15) * 64 + swz];
                acc2[0][ci] = MFMA(wffr, a2[0][kst], acc2[0][ci]);
                acc2[1][ci] = MFMA(wffr, a2[1][kst], acc2[1][ci]);
            }
        }
        // ---- vectorized stores: float4 per (ni, ci) ----
        #pragma unroll
        for (int ni = 0; ni < 2; ++ni) {
            float* op = out + ((size_t)s * RDIM + rbase + wv * 32 + ni * 16 + l15) * 64 + hi * 4;
            #pragma unroll
            for (int ci = 0; ci < 4; ++ci) {
                float4 res;
                res.x = acc2[ni][ci][0] + bff[ci][0];
                res.y = acc2[ni][ci][1] + bff[ci][1];
                res.z = acc2[ni][ci][2] + bff[ci][2];
                res.w = acc2[ni][ci][3] + bff[ci][3];
                *(float4*)(op + ci * 16) = res;
            }
        }
    }
}

extern "C" void kernel_launch(void* const* d_in, const int* in_sizes, int n_in,
                              void* d_out, int out_size, void* d_ws, size_t ws_size,
                              hipStream_t stream)
{
    const float* x   = (const float*)d_in[0];
    const float* lnw = (const float*)d_in[1];
    const float* lnb = (const float*)d_in[2];
    const float* Wq  = (const float*)d_in[3];
    const float* Wk  = (const float*)d_in[4];
    const float* Wv  = (const float*)d_in[5];
    const float* Wg  = (const float*)d_in[6];
    const float* bg  = (const float*)d_in[7];
    const float* Wf  = (const float*)d_in[8];
    const float* bf  = (const float*)d_in[9];

    char* ws = (char*)d_ws;
    float*          qpart  = (float*)ws;                        // 32*384*64 f32      @ 0        (3145728 B)
    unsigned short* kv     = (unsigned short*)(ws + 3145728);   // 384*2048*16 bf16   (25165824 B)
    float*          num    = (float*)(ws + 28311552);           // 2*384*64 f32       (196608 B)
    float*          den    = (float*)(ws + 28508160);           // 2*384*8 f32        (24576 B)
    unsigned short* ofimg  = (unsigned short*)(ws + 28532736);  // 3*256*32 bf16      (49152 B)
    unsigned short* wkvt   = (unsigned short*)(ws + 28581888);  // 16*64 bf16         (2048 B)
    unsigned short* wgt    = (unsigned short*)(ws + 28583936);  // 64*64 bf16         (8192 B)
    unsigned short* wfp    = (unsigned short*)(ws + 28592128);  // 64*64 bf16         (8192 B)
    float*          kvbias = (float*)(ws + 28600320);           // 16 f32             (64 B)
    float*          bgp    = (float*)(ws + 28600384);           // 64 f32             (256 B)

    float* outp = (float*)d_out;

    k_prep<<<3, 256, 0, stream>>>(Wk, Wv, Wg, Wf, lnw, lnb, bg, wkvt, wgt, wfp, kvbias, bgp);
    k_phase1<<<768, 256, 0, stream>>>(x, wkvt, qpart, kv);
    k_phase2a<<<768, 256, 0, stream>>>(qpart, Wq, lnw, lnb, kvbias, kv, num, den);
    k_phase2b<<<96, 256, 0, stream>>>(num, den, kvbias, ofimg);
    k_phase3<<<768, 256, 0, stream>>>(x, wgt, wfp, bgp, bf, ofimg, outp);
}